// Round 1
// 208.404 us; speedup vs baseline: 1.0196x; 1.0196x over previous
//
#include <hip/hip_runtime.h>
#include <math.h>

#define B_    2
#define NSEQ  8192
#define DIM_  512
#define H_    8
#define DH_   64
#define F_    256
#define M_    (B_*NSEQ)      // 16384
#define QKV_  1536

typedef __attribute__((ext_vector_type(8))) short     short8;
typedef __attribute__((ext_vector_type(4))) float     float4v;
typedef __attribute__((ext_vector_type(8))) unsigned short ushort8v;

__device__ __forceinline__ unsigned short f2bf(float f) {
    unsigned u = __float_as_uint(f);
    u += 0x7FFFu + ((u >> 16) & 1u);   // RNE
    return (unsigned short)(u >> 16);
}
__device__ __forceinline__ float bf2f(unsigned short h) {
    unsigned u = ((unsigned)h) << 16;
    return __uint_as_float(u);
}
// pack two floats -> two bf16 (truncate; bias cancels in N/D ratio)
__device__ __forceinline__ unsigned pack2bf(float lo, float hi) {
    return __builtin_amdgcn_perm(__float_as_uint(hi), __float_as_uint(lo), 0x07060302);
}
__device__ __forceinline__ void glds16(const void* g, void* s) {
    __builtin_amdgcn_global_load_lds(
        (const __attribute__((address_space(1))) unsigned int*)g,
        (__attribute__((address_space(3))) unsigned int*)s, 16, 0, 0);
}

// ---------------------------------------------------------------------------
// fused fp32->bf16 for all 4 inputs, one launch.
// ---------------------------------------------------------------------------
__global__ __launch_bounds__(256) void cvt_all(const float* __restrict__ x,
                                               const float* __restrict__ wqkv,
                                               const float* __restrict__ wout,
                                               const float* __restrict__ proj,
                                               unsigned short* __restrict__ xb,
                                               unsigned short* __restrict__ wqkvb,
                                               unsigned short* __restrict__ woutb,
                                               unsigned short* __restrict__ projb) {
    int bid = blockIdx.x;
    const float* in; unsigned short* out; int i;
    if (bid < 4096)      { in = x;    out = xb;    i = bid * 256 + threadIdx.x; }
    else if (bid < 4480) { in = wqkv; out = wqkvb; i = (bid - 4096) * 256 + threadIdx.x; }
    else if (bid < 4608) { in = wout; out = woutb; i = (bid - 4480) * 256 + threadIdx.x; }
    else                 { in = proj; out = projb; i = (bid - 4608) * 256 + threadIdx.x; }
    float4 a = ((const float4*)in)[2 * i];
    float4 b = ((const float4*)in)[2 * i + 1];
    ushort8v o;
    o[0] = f2bf(a.x); o[1] = f2bf(a.y); o[2] = f2bf(a.z); o[3] = f2bf(a.w);
    o[4] = f2bf(b.x); o[5] = f2bf(b.y); o[6] = f2bf(b.z); o[7] = f2bf(b.w);
    ((ushort8v*)out)[i] = o;
}

// ---------------------------------------------------------------------------
// Counted-vmcnt pipelined NT GEMM (T3/T4 minimum form + T5).
// BM=256, BN=128, BK=64, 512 threads = 8 waves (4M x 2N), per-wave 64x64.
// 3 LDS buffers (144 KB), prefetch depth 2, ONE raw s_barrier per K-tile,
// vmcnt(6) counted wait (never a full drain in the main loop).
// LDS layout: 16-row x 32-k chunks, lane-linear (conflict-free, matches the
// verified layout of the previous 2-phase kernel). K hardcoded 512 (nk=8).
// vTout: for qkv GEMM, V-columns (col>=1024) written transposed to vT.
// ---------------------------------------------------------------------------
template<bool BF16OUT>
__global__ __launch_bounds__(512) void gemm_nt_pp(const unsigned short* __restrict__ A,
                                                  const unsigned short* __restrict__ Bm,
                                                  const float* __restrict__ bias,
                                                  void* __restrict__ Cout,
                                                  unsigned short* __restrict__ vTout,
                                                  int M, int N, int K) {
    __shared__ __align__(16) unsigned short As[3][32 * 512];   // 96 KB: 256x64 per buf
    __shared__ __align__(16) unsigned short Bs[3][16 * 512];   // 48 KB: 128x64 per buf
    const int t  = threadIdx.x;
    const int w  = t >> 6, l = t & 63;
    const int wm = w >> 1, wn = w & 1;          // 4M x 2N wave grid
    const int lr = l & 15, lq = l >> 4;

    // XCD-aware remap: contiguous tile range per XCD (flat % 8 = XCD)
    const int gx = gridDim.x;
    int flat = blockIdx.y * gx + blockIdx.x;
    int per  = (gx * gridDim.y) >> 3;
    int flat2 = (flat & 7) * per + (flat >> 3);
    const int m0 = (flat2 / gx) * 256, n0 = (flat2 % gx) * 128;

    float4v acc[4][4];
#pragma unroll
    for (int mi = 0; mi < 4; mi++)
#pragma unroll
        for (int ni = 0; ni < 4; ni++) acc[mi][ni] = (float4v){0.f, 0.f, 0.f, 0.f};

    // stage one BK=64 K-tile into buffer buf: 6 glds16 per thread
    // (A: 32 chunks of 16rx32k, 4/wave; B: 16 chunks, 2/wave)
    auto stage = [&](int buf, int k0) {
#pragma unroll
        for (int i = 0; i < 4; i++) {
            int c = w * 4 + i, rb = c >> 1, ks = c & 1;
            glds16(A + (size_t)(m0 + rb * 16 + lr) * K + k0 + ks * 32 + lq * 8,
                   &As[buf][c * 512]);
        }
#pragma unroll
        for (int i = 0; i < 2; i++) {
            int c = w * 2 + i, rb = c >> 1, ks = c & 1;
            glds16(Bm + (size_t)(n0 + rb * 16 + lr) * K + k0 + ks * 32 + lq * 8,
                   &Bs[buf][c * 512]);
        }
    };

    stage(0, 0);      // tile 0 in flight (6 loads)
    stage(1, 64);     // tile 1 in flight (12 loads)

    // K = 512 for both GEMMs -> nk = 8 (fully unrolled)
#pragma unroll
    for (int k = 0; k < 8; k++) {
        // counted wait: tile k landed, tile k+1 (6 youngest) may stay in flight
        if (k < 7) { asm volatile("s_waitcnt vmcnt(6)" ::: "memory"); }
        else       { asm volatile("s_waitcnt vmcnt(0)" ::: "memory"); }
        __builtin_amdgcn_s_barrier();
        const int cur = k % 3;

        // issue next-next tile's loads first (overlap HBM latency w/ compute)
        if (k + 2 < 8) stage((k + 2) % 3, (k + 2) << 6);

        short8 af[2][4], bfr[2][4];
#pragma unroll
        for (int ks = 0; ks < 2; ks++) {
#pragma unroll
            for (int mi = 0; mi < 4; mi++)
                af[ks][mi] = *(const short8*)&As[cur][(((wm * 4 + mi) * 2 + ks) * 64 + l) * 8];
#pragma unroll
            for (int ni = 0; ni < 4; ni++)
                bfr[ks][ni] = *(const short8*)&Bs[cur][(((wn * 4 + ni) * 2 + ks) * 64 + l) * 8];
        }

        __builtin_amdgcn_s_setprio(1);
#pragma unroll
        for (int ks = 0; ks < 2; ks++)
#pragma unroll
            for (int mi = 0; mi < 4; mi++)
#pragma unroll
                for (int ni = 0; ni < 4; ni++)
                    acc[mi][ni] = __builtin_amdgcn_mfma_f32_16x16x32_bf16(
                        af[ks][mi], bfr[ks][ni], acc[mi][ni], 0, 0, 0);
        __builtin_amdgcn_s_setprio(0);
    }

    const int q = l >> 4, c = l & 15;      // C/D: col=lane&15, row=quad*4+reg
#pragma unroll
    for (int mi = 0; mi < 4; mi++) {
        int row0 = m0 + wm * 64 + mi * 16 + q * 4;
#pragma unroll
        for (int ni = 0; ni < 4; ni++) {
            int col = n0 + wn * 64 + ni * 16 + c;
            if (BF16OUT && vTout != nullptr && col >= 1024) {
                // V path: write transposed into vT[z=b*8+h][dh][seq]
                int cm = col - 1024;
                int h2 = cm >> 6, dh = cm & 63;
                int bq = row0 >> 13;
                size_t nn = (size_t)(row0 & 8191);
                unsigned short* dst = vTout + (((size_t)bq * 8 + h2) * 64 + dh) * NSEQ + nn;
                uint2 pv;
                pv.x = ((unsigned)f2bf(acc[mi][ni][1]) << 16) | f2bf(acc[mi][ni][0]);
                pv.y = ((unsigned)f2bf(acc[mi][ni][3]) << 16) | f2bf(acc[mi][ni][2]);
                *(uint2*)dst = pv;
            } else {
                float bv = bias ? bias[col] : 0.f;
#pragma unroll
                for (int r = 0; r < 4; r++) {
                    float v = acc[mi][ni][r] + bv;
                    if (BF16OUT) ((unsigned short*)Cout)[(size_t)(row0 + r) * N + col] = f2bf(v);
                    else         ((float*)Cout)[(size_t)(row0 + r) * N + col] = v;
                }
            }
        }
    }
}

// ---------------------------------------------------------------------------
// Fused k' featuremap + split-K context via MFMA (round-7 verified version).
// grid (16 s, 2 fh, 16 z); LDS 48 KB -> 3 blocks/CU.
// ---------------------------------------------------------------------------
__global__ __launch_bounds__(256) void ctx_fused_mfma(
    const unsigned short* __restrict__ qkvb,
    const unsigned short* __restrict__ projb,
    const unsigned short* __restrict__ vT,
    unsigned short* __restrict__ partial)   // [16 s][16 z][80][256] bf16
{
    __shared__ __align__(16) unsigned short PB[16 * 512];   // proj B-frags (f-half, resident)
    __shared__ __align__(16) unsigned short KB[8 * 512];    // K-rows A-frags (per step)
    __shared__ __align__(16) unsigned short VB[8 * 512];    // vT B-frags (per step)
    __shared__ __align__(16) unsigned short KPA[16 * 512];  // kp A-frags (f-half)
    const int t = threadIdx.x, w = t >> 6, l = t & 63;
    const int lr = l & 15, lq = l >> 4;
    const int s = blockIdx.x, fh = blockIdx.y, z = blockIdx.z;
    const int b = z >> 3, h = z & 7;
    const int nchunk = s * 512;

    for (int idx = w; idx < 16; idx += 4) {
        int fblk = idx >> 1, kt = idx & 1;
        glds16(projb + (size_t)(fh * 128 + fblk * 16 + lr) * 64 + kt * 32 + lq * 8, &PB[idx * 512]);
    }

    float4v acc[2][5];
#pragma unroll
    for (int mi = 0; mi < 2; mi++)
#pragma unroll
        for (int ni = 0; ni < 5; ni++) acc[mi][ni] = (float4v){0.f, 0.f, 0.f, 0.f};
    short ov = (lr == 0) ? (short)0x3F80 : (short)0;
    short8 ones = {ov, ov, ov, ov, ov, ov, ov, ov};

    for (int st = 0; st < 8; st++) {
        int nbase = nchunk + st * 64;
        __syncthreads();
        for (int idx = w; idx < 8; idx += 4) {
            int nblk = idx >> 1, kt = idx & 1;
            glds16(qkvb + ((size_t)b * NSEQ + nbase + nblk * 16 + lr) * QKV_ + 512 + h * 64 + kt * 32 + lq * 8,
                   &KB[idx * 512]);
        }
        for (int idx = w; idx < 8; idx += 4) {
            int dhb = idx >> 1, nt2 = idx & 1;
            glds16(vT + ((size_t)z * 64 + dhb * 16 + lr) * NSEQ + nbase + nt2 * 32 + lq * 8,
                   &VB[idx * 512]);
        }
        __syncthreads();

        // phase A: rows n (mi 0..3), cols f' (wave w: 32 f, ni 0..1)
        float4v a2[4][2];
#pragma unroll
        for (int mi = 0; mi < 4; mi++)
#pragma unroll
            for (int ni = 0; ni < 2; ni++) a2[mi][ni] = (float4v){0.f, 0.f, 0.f, 0.f};
#pragma unroll
        for (int ks = 0; ks < 2; ks++) {
            short8 ka[4], pb[2];
#pragma unroll
            for (int mi = 0; mi < 4; mi++)
                ka[mi] = *(const short8*)&KB[((mi * 2 + ks) * 64 + l) * 8];
#pragma unroll
            for (int ni = 0; ni < 2; ni++)
                pb[ni] = *(const short8*)&PB[(((w * 2 + ni) * 2 + ks) * 64 + l) * 8];
#pragma unroll
            for (int mi = 0; mi < 4; mi++)
#pragma unroll
                for (int ni = 0; ni < 2; ni++)
                    a2[mi][ni] = __builtin_amdgcn_mfma_f32_16x16x32_bf16(ka[mi], pb[ni], a2[mi][ni], 0, 0, 0);
        }
        // exp -> bf16 -> KPA (A-frag order, local f' = w*32 + ni*16 + lr)
#pragma unroll
        for (int mi = 0; mi < 4; mi++) {
            int nb = mi * 16 + lq * 4;
            int qoff = ((nb >> 3) & 3) * 256 + (nb & 7) * 2;
            int setn = nb >> 5;
#pragma unroll
            for (int ni = 0; ni < 2; ni++) {
                int fp = w * 32 + ni * 16 + lr;
                float e0 = __expf(a2[mi][ni][0]);
                float e1 = __expf(a2[mi][ni][1]);
                float e2 = __expf(a2[mi][ni][2]);
                float e3 = __expf(a2[mi][ni][3]);
                uint2 p; p.x = pack2bf(e0, e1); p.y = pack2bf(e2, e3);
                *(uint2*)((char*)KPA + (size_t)(((fp >> 4) * 2 + setn) * 1024 + qoff + (fp & 15) * 16)) = p;
            }
        }
        // phase B: rows f' (wave w: mi 0..1), cols dh_ext (ni; ni=4 -> ksum)
#pragma unroll
        for (int ks = 0; ks < 2; ks++) {
            short8 af[2], bf[4];
#pragma unroll
            for (int mi = 0; mi < 2; mi++)
                af[mi] = *(const short8*)&KPA[(((w * 2 + mi) * 2 + ks) * 64 + l) * 8];
#pragma unroll
            for (int ni = 0; ni < 4; ni++)
                bf[ni] = *(const short8*)&VB[((ni * 2 + ks) * 64 + l) * 8];
#pragma unroll
            for (int mi = 0; mi < 2; mi++) {
#pragma unroll
                for (int ni = 0; ni < 4; ni++)
                    acc[mi][ni] = __builtin_amdgcn_mfma_f32_16x16x32_bf16(af[mi], bf[ni], acc[mi][ni], 0, 0, 0);
                acc[mi][4] = __builtin_amdgcn_mfma_f32_16x16x32_bf16(af[mi], ones, acc[mi][4], 0, 0, 0);
            }
        }
    }
    unsigned short* base = partial + (size_t)(s * 16 + z) * 80 * 256 + fh * 128;
#pragma unroll
    for (int mi = 0; mi < 2; mi++) {
        int f0r = w * 32 + mi * 16 + lq * 4;
#pragma unroll
        for (int ni = 0; ni < 5; ni++) {
            int col = ni * 16 + lr;
#pragma unroll
            for (int r = 0; r < 4; r++)
                base[(size_t)col * 256 + f0r + r] = f2bf(acc[mi][ni][r]);
        }
    }
}

// ---------------------------------------------------------------------------
// Reduce split-K bf16 partials (16 splits) -> ctxT bf16 [z][80][256].
// ---------------------------------------------------------------------------
__global__ __launch_bounds__(256) void ctx_reduce(const unsigned short* __restrict__ partial,
                                                  unsigned short* __restrict__ ctxT) {
    int idx8 = blockIdx.x * 256 + threadIdx.x;   // 0 .. 40959
    const int INNER = 16 * 80 * 256;
    size_t off = (size_t)idx8 * 8;
    float s0 = 0.f, s1 = 0.f, s2 = 0.f, s3 = 0.f, s4 = 0.f, s5 = 0.f, s6 = 0.f, s7 = 0.f;
#pragma unroll
    for (int k = 0; k < 16; k++) {
        ushort8v v = *(const ushort8v*)(partial + (size_t)k * INNER + off);
        s0 += bf2f(v[0]); s1 += bf2f(v[1]); s2 += bf2f(v[2]); s3 += bf2f(v[3]);
        s4 += bf2f(v[4]); s5 += bf2f(v[5]); s6 += bf2f(v[6]); s7 += bf2f(v[7]);
    }
    ushort8v o;
    o[0] = f2bf(s0); o[1] = f2bf(s1); o[2] = f2bf(s2); o[3] = f2bf(s3);
    o[4] = f2bf(s4); o[5] = f2bf(s5); o[6] = f2bf(s6); o[7] = f2bf(s7);
    *(ushort8v*)(ctxT + off) = o;
}

// ---------------------------------------------------------------------------
// Fused q' featuremap + (q'.ctx_ext) with D at col 64 -> bf16 attn out.
// (round-7 verified version, unchanged)
// ---------------------------------------------------------------------------
__global__ __launch_bounds__(256) void attn_fused_mfma(
    const unsigned short* __restrict__ qkvb,
    const unsigned short* __restrict__ projb,
    const unsigned short* __restrict__ ctxT,
    unsigned short* __restrict__ attnb)
{
    __shared__ __align__(16) unsigned short QB[16 * 512];
    __shared__ __align__(16) unsigned short PA[8 * 512];
    __shared__ __align__(16) unsigned short QPA[16 * 512];
    __shared__ __align__(16) unsigned short CB[10 * 512];
    const int t = threadIdx.x, w = t >> 6, l = t & 63;
    const int lr = l & 15, lq = l >> 4;
    const int m0 = blockIdx.x * 128, z = blockIdx.y;
    const int b = z >> 3, h = z & 7;

    for (int idx = w; idx < 16; idx += 4) {
        int mblk = idx >> 1, kt = idx & 1;
        glds16(qkvb + ((size_t)b * NSEQ + m0 + mblk * 16 + lr) * QKV_ + h * 64 + kt * 32 + lq * 8,
               &QB[idx * 512]);
    }
    float4v acc[2][5];
#pragma unroll
    for (int mi = 0; mi < 2; mi++)
#pragma unroll
        for (int ni = 0; ni < 5; ni++) acc[mi][ni] = (float4v){0.f, 0.f, 0.f, 0.f};

    for (int fs = 0; fs < 4; fs++) {
        int f0 = fs * 64;
        __syncthreads();
        for (int idx = w; idx < 8; idx += 4) {
            int fb = idx >> 1, kt = idx & 1;
            glds16(projb + (size_t)(f0 + fb * 16 + lr) * 64 + kt * 32 + lq * 8, &PA[idx * 512]);
        }
        for (int idx = w; idx < 10; idx += 4) {
            int dhb = idx >> 1, ft = idx & 1;
            glds16(ctxT + ((size_t)z * 80 + dhb * 16 + lr) * 256 + f0 + ft * 32 + lq * 8,
                   &CB[idx * 512]);
        }
        __syncthreads();

        float4v a2[4][2];
#pragma unroll
        for (int mi = 0; mi < 4; mi++)
#pragma unroll
            for (int ni = 0; ni < 2; ni++) a2[mi][ni] = (float4v){0.f, 0.f, 0.f, 0.f};
#pragma unroll
        for (int ks = 0; ks < 2; ks++) {
            short8 pa[4], qb[2];
#pragma unroll
            for (int mi = 0; mi < 4; mi++)
                pa[mi] = *(const short8*)&PA[((mi * 2 + ks) * 64 + l) * 8];
#pragma unroll
            for (int ni = 0; ni < 2; ni++)
                qb[ni] = *(const short8*)&QB[(((w * 2 + ni) * 2 + ks) * 64 + l) * 8];
#pragma unroll
            for (int mi = 0; mi < 4; mi++)
#pragma unroll
                for (int ni = 0; ni < 2; ni++)
                    a2[mi][ni] = __builtin_amdgcn_mfma_f32_16x16x32_bf16(pa[mi], qb[ni], a2[mi][ni], 0, 0, 0);
        }
#pragma unroll
        for (int mi = 0; mi < 4; mi++) {
            int fb2 = mi * 16 + lq * 4;
            int qoff = ((fb2 >> 3) & 3) * 256 + (fb2 & 7) * 2;
            int setf = fb2 >> 5;
#pragma unroll
            for (int ni = 0; ni < 2; ni++) {
                int m = w * 32 + ni * 16 + lr;
                float e0 = __expf(0.125f * a2[mi][ni][0]);
                float e1 = __expf(0.125f * a2[mi][ni][1]);
                float e2 = __expf(0.125f * a2[mi][ni][2]);
                float e3 = __expf(0.125f * a2[mi][ni][3]);
                uint2 p; p.x = pack2bf(e0, e1); p.y = pack2bf(e2, e3);
                *(uint2*)((char*)QPA + (size_t)(((m >> 4) * 2 + setf) * 1024 + qoff + (m & 15) * 16)) = p;
            }
        }
#pragma unroll
        for (int ks = 0; ks < 2; ks++) {
            short8 af[2], cb[5];
#pragma unroll
            for (int mi = 0; mi < 2; mi++)
                af[mi] = *(const short8*)&QPA[(((w * 2 + mi) * 2 + ks) * 64 + l) * 8];
#pragma unroll
            for (int ni = 0; ni < 5; ni++)
                cb[ni] = *(const short8*)&CB[((ni * 2 + ks) * 64 + l) * 8];
#pragma unroll
            for (int mi = 0; mi < 2; mi++)
#pragma unroll
                for (int ni = 0; ni < 5; ni++)
                    acc[mi][ni] = __builtin_amdgcn_mfma_f32_16x16x32_bf16(af[mi], cb[ni], acc[mi][ni], 0, 0, 0);
        }
    }
#pragma unroll
    for (int mi = 0; mi < 2; mi++) {
        int rowb = m0 + w * 32 + mi * 16 + lq * 4;
#pragma unroll
        for (int r = 0; r < 4; r++) {
            float dv = __shfl(acc[mi][4][r], (l & 48), 64);
            float rinv = 1.f / (dv + 1e-6f);
#pragma unroll
            for (int ni = 0; ni < 4; ni++)
                attnb[((size_t)b * NSEQ + rowb + r) * 512 + h * 64 + ni * 16 + lr] =
                    f2bf(acc[mi][ni][r] * rinv);
        }
    }
}

// ---------------------------------------------------------------------------
extern "C" void kernel_launch(void* const* d_in, const int* in_sizes, int n_in,
                              void* d_out, int out_size, void* d_ws, size_t ws_size,
                              hipStream_t stream) {
    const float* x    = (const float*)d_in[0];
    const float* Wqkv = (const float*)d_in[1];
    const float* Wout = (const float*)d_in[2];
    const float* bout = (const float*)d_in[3];
    const float* proj = (const float*)d_in[4];

    unsigned short* qkvb    = (unsigned short*)d_ws;                 // 25,165,824 u16
    unsigned short* vT      = qkvb + (size_t)M_ * QKV_;              // 8,388,608 u16
    unsigned short* partial = vT + (size_t)16 * 64 * NSEQ;           // 5,242,880 u16 (bf16, 16 splits)
    unsigned short* ctxT    = partial + (size_t)16 * 16 * 80 * 256;  // 327,680 u16
    unsigned short* projb   = ctxT + (size_t)16 * 80 * 256;          // 16,384 u16
    unsigned short* xb      = projb + 16384;                         // 8,388,608 u16
    unsigned short* attnb   = xb;                                    // overlay (xb dead after gemm1)
    unsigned short* wqkvb   = xb + (size_t)M_ * DIM_;                // 786,432 u16
    unsigned short* woutb   = wqkvb + (size_t)QKV_ * DIM_;           // 262,144 u16
    float* outp = (float*)d_out;                                     // total ws ~97 MB

    // 0) fp32 -> bf16 (single launch)
    cvt_all<<<dim3(4616), 256, 0, stream>>>(x, Wqkv, Wout, proj, xb, wqkvb, woutb, projb);
    // 1) qkv = x @ Wqkv^T — Q/K cols -> qkvb, V cols -> vT (fused transpose)
    //    BM=256 x BN=128 pipelined: grid (12, 64) = 768 blocks (3/CU, %8==0)
    gemm_nt_pp<true><<<dim3(QKV_ / 128, M_ / 256), 512, 0, stream>>>(xb, wqkvb, nullptr, qkvb, vT, M_, QKV_, DIM_);
    // 2) fused k' + context partials (16 splits, 8 n-steps/block)
    ctx_fused_mfma<<<dim3(16, 2, 16), 256, 0, stream>>>(qkvb, projb, vT, partial);
    // 3) reduce -> ctxT bf16 (incl. ksum row)
    ctx_reduce<<<dim3(160), 256, 0, stream>>>(partial, ctxT);
    // 4) fused q' + attention out (MFMA), bf16
    attn_fused_mfma<<<dim3(64, 16), 256, 0, stream>>>(qkvb, projb, ctxT, attnb);
    // 5) out = attn @ Wout^T + bout — grid (4, 64) = 256 blocks (1/CU, %8==0)
    gemm_nt_pp<false><<<dim3(DIM_ / 128, M_ / 256), 512, 0, stream>>>(attnb, woutb, bout, outp, nullptr, M_, DIM_, DIM_);
}